// Round 4
// baseline (79.884 us; speedup 1.0000x reference)
//
#include <hip/hip_runtime.h>

#define DEG 16
#define ATOMS_PER_BLOCK 16

// Prep: pack position xyz + element (as float) into one 16B record per atom,
// so the main kernel's random neighbor gather is a single global_load_dwordx4.
__global__ __launch_bounds__(256) void mbp_pack_kernel(
    const float* __restrict__ pos, const int* __restrict__ elem,
    float4* __restrict__ pack4, int n_atoms)
{
    const int i = blockIdx.x * 256 + threadIdx.x;
    if (i < n_atoms) {
        pack4[i] = make_float4(pos[i * 3 + 0], pos[i * 3 + 1], pos[i * 3 + 2],
                               (float)elem[i]);
    }
}

__global__ __launch_bounds__(256) void ManyBodyPotential_85143431675992_kernel(
    const float4* __restrict__ pack4,   // (n_atoms,) x,y,z,elem — packed
    const int*    __restrict__ target,  // (n_atoms*DEG,) = edge_index[1]
    const int*    __restrict__ plt,     // (3,3) row-major, symmetric
    const float*  __restrict__ k_angle, // (6,)
    const float*  __restrict__ cos0,    // (6,)
    float*        __restrict__ partials,// (gridDim.x,)
    int n_atoms)
{
    __shared__ float  ka_tab[9];
    __shared__ float  c0_tab[9];
    // Per neighbor: unit vector + element-as-float in .w  (ds_read_b128)
    __shared__ float4 s4[ATOMS_PER_BLOCK][DEG + 1];   // +1 float4 row pad
    __shared__ float  wsum[4];

    const int t = threadIdx.x;
    if (t < 9) {
        const int p = plt[t];
        ka_tab[t] = k_angle[p];
        c0_tab[t] = cos0[p];
    }

    const int a    = t >> 4;             // local atom 0..15
    const int j    = t & 15;             // neighbor slot 0..15
    const int atom = blockIdx.x * ATOMS_PER_BLOCK + a;
    const bool active = (atom < n_atoms);

    float ux = 0.f, uy = 0.f, uz = 0.f;
    int   ej = 0;
    if (active) {
        const float4 me = pack4[atom];             // dwordx4, 16-thread broadcast
        const int    tj = target[atom * DEG + j];  // coalesced dword
        const float4 nb = pack4[tj];               // THE gather: one dwordx4
        const float dx = nb.x - me.x;
        const float dy = nb.y - me.y;
        const float dz = nb.z - me.z;
        const float r2 = dx * dx + dy * dy + dz * dz;
        // r2==0 (self-edge): reference gives cos=0 for pairs on this edge;
        // zero unit vector reproduces that exactly.
        const float rinv = (r2 > 0.f) ? rsqrtf(r2) : 0.f;
        ux = dx * rinv; uy = dy * rinv; uz = dz * rinv;
        ej = (int)nb.w;
        s4[a][j] = make_float4(ux, uy, uz, nb.w);
    }
    __syncthreads();

    float acc = 0.0f;
    if (active) {
        // Hoist this thread's (ej, *) coefficient row into registers.
        const int   r   = ej * 3;
        const float ka0 = ka_tab[r + 0], ka1 = ka_tab[r + 1], ka2 = ka_tab[r + 2];
        const float c00 = c0_tab[r + 0], c01 = c0_tab[r + 1], c02 = c0_tab[r + 2];

        // Symmetry: e(j,k)==e(k,j).  Offsets d=1..7 cover each unordered
        // pair once (weight 2); d=8 pairs appear twice across j (weight 1).
        float acc2 = 0.0f, acc8 = 0.0f;
        #pragma unroll
        for (int d = 1; d <= 8; ++d) {
            const int    k  = (j + d) & 15;
            const float4 o  = s4[a][k];
            const float  ka = (o.w == 1.0f) ? ka1 : ((o.w == 2.0f) ? ka2 : ka0);
            const float  c0 = (o.w == 1.0f) ? c01 : ((o.w == 2.0f) ? c02 : c00);
            const float  ct = ux * o.x + uy * o.y + uz * o.z;   // cos(theta)
            const float  dd = ct - c0;
            const float  e  = ka * dd * dd;
            if (d < 8) acc2 += e; else acc8 = e;
        }
        acc = 2.0f * acc2 + acc8;
    }

    // Wave(64) shuffle -> block -> one partial per block (no contention).
    #pragma unroll
    for (int off = 32; off > 0; off >>= 1)
        acc += __shfl_down(acc, off, 64);
    if ((t & 63) == 0) wsum[t >> 6] = acc;
    __syncthreads();
    if (t == 0) {
        partials[blockIdx.x] = wsum[0] + wsum[1] + wsum[2] + wsum[3];
    }
}

__global__ __launch_bounds__(1024) void mbp_reduce_kernel(
    const float* __restrict__ partials, float* __restrict__ out, int n)
{
    __shared__ float wsum[16];
    const int t = threadIdx.x;
    float acc = 0.0f;
    for (int i = t; i < n; i += 1024) acc += partials[i];
    #pragma unroll
    for (int off = 32; off > 0; off >>= 1)
        acc += __shfl_down(acc, off, 64);
    if ((t & 63) == 0) wsum[t >> 6] = acc;
    __syncthreads();
    if (t == 0) {
        float s = 0.0f;
        #pragma unroll
        for (int i = 0; i < 16; ++i) s += wsum[i];
        out[0] = s;
    }
}

// ---- Fallback path (ws too small): R2-style unpacked kernel with atomics ----
__global__ void mbp_zero_kernel(float* out) {
    if (threadIdx.x == 0) out[0] = 0.0f;
}

__global__ __launch_bounds__(256) void mbp_fallback_kernel(
    const float* __restrict__ pos, const int* __restrict__ target,
    const int* __restrict__ elem, const int* __restrict__ plt,
    const float* __restrict__ k_angle, const float* __restrict__ cos0,
    float* __restrict__ out, int n_atoms)
{
    __shared__ float  ka_tab[9];
    __shared__ float  c0_tab[9];
    __shared__ float4 s4[ATOMS_PER_BLOCK][DEG + 1];
    __shared__ float  wsum[4];
    const int t = threadIdx.x;
    if (t < 9) { const int p = plt[t]; ka_tab[t] = k_angle[p]; c0_tab[t] = cos0[p]; }
    const int a = t >> 4, j = t & 15;
    const int atom = blockIdx.x * ATOMS_PER_BLOCK + a;
    const bool active = (atom < n_atoms);
    float ux = 0.f, uy = 0.f, uz = 0.f; int ej = 0;
    if (active) {
        const float pix = pos[atom * 3], piy = pos[atom * 3 + 1], piz = pos[atom * 3 + 2];
        const int tj = target[atom * DEG + j];
        const float dx = pos[tj * 3] - pix, dy = pos[tj * 3 + 1] - piy, dz = pos[tj * 3 + 2] - piz;
        const float r2 = dx * dx + dy * dy + dz * dz;
        const float rinv = (r2 > 0.f) ? rsqrtf(r2) : 0.f;
        ux = dx * rinv; uy = dy * rinv; uz = dz * rinv;
        ej = elem[tj];
        s4[a][j] = make_float4(ux, uy, uz, (float)ej);
    }
    __syncthreads();
    float acc = 0.0f;
    if (active) {
        const int r = ej * 3;
        const float ka0 = ka_tab[r], ka1 = ka_tab[r + 1], ka2 = ka_tab[r + 2];
        const float c00 = c0_tab[r], c01 = c0_tab[r + 1], c02 = c0_tab[r + 2];
        float acc2 = 0.f, acc8 = 0.f;
        #pragma unroll
        for (int d = 1; d <= 8; ++d) {
            const int k = (j + d) & 15;
            const float4 o = s4[a][k];
            const float ka = (o.w == 1.0f) ? ka1 : ((o.w == 2.0f) ? ka2 : ka0);
            const float c0 = (o.w == 1.0f) ? c01 : ((o.w == 2.0f) ? c02 : c00);
            const float ct = ux * o.x + uy * o.y + uz * o.z;
            const float dd = ct - c0;
            const float e = ka * dd * dd;
            if (d < 8) acc2 += e; else acc8 = e;
        }
        acc = 2.0f * acc2 + acc8;
    }
    #pragma unroll
    for (int off = 32; off > 0; off >>= 1) acc += __shfl_down(acc, off, 64);
    if ((t & 63) == 0) wsum[t >> 6] = acc;
    __syncthreads();
    if (t == 0) atomicAdd(out, wsum[0] + wsum[1] + wsum[2] + wsum[3]);
}

extern "C" void kernel_launch(void* const* d_in, const int* in_sizes, int n_in,
                              void* d_out, int out_size, void* d_ws, size_t ws_size,
                              hipStream_t stream) {
    const float* pos     = (const float*)d_in[0];
    const int*   edge    = (const int*)d_in[1];   // (2, n_edges) flat
    const int*   elem    = (const int*)d_in[2];
    const int*   plt     = (const int*)d_in[3];
    const float* k_angle = (const float*)d_in[4];
    const float* cos0    = (const float*)d_in[5];
    float*       out     = (float*)d_out;

    const int n_atoms = in_sizes[0] / 3;
    const int n_edges = in_sizes[1] / 2;
    const int* target = edge + n_edges;           // edge_index[1]

    const int n_blocks   = (n_atoms + ATOMS_PER_BLOCK - 1) / ATOMS_PER_BLOCK; // 3125
    const int pack_pad   = ((n_atoms + 255) / 256) * 256;   // float4-aligned slots
    const size_t need    = (size_t)pack_pad * sizeof(float4)
                         + (size_t)n_blocks * sizeof(float);
    const bool ws_ok = (d_ws != nullptr) && (ws_size >= need);

    if (ws_ok) {
        float4* pack4    = (float4*)d_ws;
        float*  partials = (float*)((char*)d_ws + (size_t)pack_pad * sizeof(float4));

        mbp_pack_kernel<<<(n_atoms + 255) / 256, 256, 0, stream>>>(
            pos, elem, pack4, n_atoms);
        ManyBodyPotential_85143431675992_kernel<<<n_blocks, 256, 0, stream>>>(
            pack4, target, plt, k_angle, cos0, partials, n_atoms);
        mbp_reduce_kernel<<<1, 1024, 0, stream>>>(partials, out, n_blocks);
    } else {
        mbp_zero_kernel<<<1, 64, 0, stream>>>(out);
        mbp_fallback_kernel<<<n_blocks, 256, 0, stream>>>(
            pos, target, elem, plt, k_angle, cos0, out, n_atoms);
    }
}